// Round 6
// baseline (3314.891 us; speedup 1.0000x reference)
//
#include <hip/hip_runtime.h>
#include <cmath>

#define NR   8192   // rows of Y
#define DB   512    // signal dim n
#define NB   2048   // dictionary atoms m
#define ITERS 20
#define NSQ   9     // trace-normalized squarings of B

typedef _Float16 hfrag_t __attribute__((ext_vector_type(8)));  // 8 fp16 = 16B
typedef __attribute__((ext_vector_type(4))) float accv_t;      // 4 fp32
typedef unsigned short us4 __attribute__((ext_vector_type(4))); // 8B
typedef unsigned short us8 __attribute__((ext_vector_type(8))); // 16B
typedef float f4 __attribute__((ext_vector_type(4)));           // 16B

// scalar slots in ws
#define SL_Y2   0
#define SL_NUM  1
#define SL_DEN  2
#define SL_C    3
#define SL_ETA  4
#define SL_THR  5
#define SL_TR   6    // 6..15  traces
#define SL_RES2 16   // 16..35 per-iter ||R||^2

__device__ inline unsigned short f2h(float f) {
  _Float16 h = (_Float16)f;
  return __builtin_bit_cast(unsigned short, h);
}
__device__ inline float h2f(unsigned short u) {
  _Float16 h = __builtin_bit_cast(_Float16, u);
  return (float)h;
}
__device__ inline float softthr(float x, float t) {
  float a = fabsf(x) - t;
  return a > 0.f ? copysignf(a, x) : 0.f;
}

// ---- Fragment-native tiled layout ----
// 16x16 tile = 256 contiguous fp16, element (m,k) at m*16+k (row-major in tile).
// A-fragment for mfma_16x16x32 (operand-swapped): lane (l16,quad) needs
// A[m=l16][k=quad*8+j] j=0..7 -> tile kt*2+(quad>>1), bytes l16*32+(quad&1)*16:
// ONE 16B load per fragment; wave covers 512B contiguous. Same for B (n,k).
// C tile: lane owns (m=l16, n=quad*4+r) -> us4 at byte l16*32+quad*8.

// ---- barrier-free MFMA GEMM core: both operands tiled, no LDS ----
// EXACT round-0 proven text (VGPR 64-68, good compiler schedule). Do not
// restructure: lambda/UNR/launch_bounds variants all regressed (r1, r5).
template<int MI, int NI, int NKT>
__device__ inline void gemm_tt(const unsigned short* __restrict__ At, int NTka,
                               const unsigned short* __restrict__ Bt, int NTkb,
                               int mt0, int nt0, accv_t acc[MI][NI]) {
  const int lane = threadIdx.x & 63;
  const int l16 = lane & 15, quad = lane >> 4;
  const int off = l16 * 16 + (quad & 1) * 8;   // element offset within tile
  const int kh = quad >> 1;
#pragma unroll
  for (int mi = 0; mi < MI; ++mi)
#pragma unroll
    for (int ni = 0; ni < NI; ++ni) acc[mi][ni] = (accv_t){0.f, 0.f, 0.f, 0.f};

#pragma unroll 4
  for (int kt = 0; kt < NKT; ++kt) {
    const int ktile = (kt << 1) + kh;
    hfrag_t af[MI], bf[NI];
#pragma unroll
    for (int mi = 0; mi < MI; ++mi)
      af[mi] = *(const hfrag_t*)&At[(((size_t)(mt0 + mi) * NTka + ktile) << 8) + off];
#pragma unroll
    for (int ni = 0; ni < NI; ++ni)
      bf[ni] = *(const hfrag_t*)&Bt[(((size_t)(nt0 + ni) * NTkb + ktile) << 8) + off];
#pragma unroll
    for (int mi = 0; mi < MI; ++mi)
#pragma unroll
      for (int ni = 0; ni < NI; ++ni)
        acc[mi][ni] = __builtin_amdgcn_mfma_f32_16x16x32_f16(bf[ni], af[mi], acc[mi][ni], 0, 0, 0);
  }
}

// C-tile epilogue offset (element units) for tiled fp16 surfaces
__device__ inline size_t ctile_off(int mt, int nt, int NTn) {
  int lane = threadIdx.x & 63;
  return (((size_t)mt * NTn + nt) << 8) + (lane & 15) * 16 + (lane >> 4) * 4;
}

// ---------------- small kernels ----------------
__global__ void k_zero(float* slots, float* colsq) {
  if (threadIdx.x < 64) slots[threadIdx.x] = 0.f;
  for (int i = threadIdx.x; i < NB; i += 256) colsq[i] = 0.f;
}

// column sum-of-squares, row-split partials (grid (8 colgroups, 8 rowgroups))
__global__ void k_colsq(const float* __restrict__ W, float* __restrict__ colsq) {
  int j = blockIdx.x * 256 + threadIdx.x;     // column
  int r0 = blockIdx.y * 64;
  float s = 0.f;
  for (int i = 0; i < 64; ++i) { float v = W[(size_t)(r0 + i) * NB + j]; s += v * v; }
  atomicAdd(&colsq[j], s);
}

// normalize cols; emit tiled Wn_t [DB/16][NB/16] (elem (i,j)->i*16+j)
// and tiled Wt_t [NB/16][DB/16] (elem (j,i)->j*16+i)
__global__ void k_wnorm(const float* __restrict__ W, const float* __restrict__ colsq,
                        unsigned short* __restrict__ Wn_t, unsigned short* __restrict__ Wt_t) {
  int tx = threadIdx.x & 31, ty = threadIdx.x >> 5;
  int j = blockIdx.x * 32 + tx;               // NB index
  float inv = 1.0f / sqrtf(colsq[j]);
#pragma unroll
  for (int r = 0; r < 4; ++r) {
    int i = blockIdx.y * 32 + ty + r * 8;     // DB index
    unsigned short h = f2h(W[(size_t)i * NB + j] * inv);
    Wn_t[(((size_t)(i >> 4) * (NB / 16) + (j >> 4)) << 8) + (i & 15) * 16 + (j & 15)] = h;
    Wt_t[(((size_t)(j >> 4) * (DB / 16) + (i >> 4)) << 8) + (j & 15) * 16 + (i & 15)] = h;
  }
}

// Y (row-major fp32) -> Yh (tiled fp16) + ||Y||^2.
// Wave-per-row: fully coalesced 2KB reads; one atomic per block.
__global__ __launch_bounds__(256) void k_ynorm(const float* __restrict__ Y,
                                               unsigned short* __restrict__ Yh,
                                               float* __restrict__ slots) {
  __shared__ float part[4];
  int w = threadIdx.x >> 6, lane = threadIdx.x & 63;
  float s = 0.f;
#pragma unroll
  for (int rr = 0; rr < 4; ++rr) {
    int m = blockIdx.x * 16 + w * 4 + rr;     // 512 blocks x 16 rows
    const float* yrow = &Y[(size_t)m * DB + lane * 8];
    f4 v0 = *(const f4*)yrow;
    f4 v1 = *(const f4*)(yrow + 4);
    us8 h;
#pragma unroll
    for (int q = 0; q < 4; ++q) {
      h[q] = f2h(v0[q]);     s += v0[q] * v0[q];
      h[4 + q] = f2h(v1[q]); s += v1[q] * v1[q];
    }
    *(us8*)&Yh[(((size_t)(m >> 4) * 32 + (lane >> 1)) << 8) + (m & 15) * 16 + (lane & 1) * 8] = h;
  }
  for (int off = 32; off > 0; off >>= 1) s += __shfl_xor(s, off);
  if (lane == 0) part[w] = s;
  __syncthreads();
  if (threadIdx.x == 0) atomicAdd(&slots[SL_Y2], part[0] + part[1] + part[2] + part[3]);
}

// fp32 squaring: D = (S/tr)^2, accumulate trace(D)
__global__ __launch_bounds__(256) void k_sq(const float* __restrict__ S, float* __restrict__ D,
                                            const float* __restrict__ trIn, float* __restrict__ trOut) {
  __shared__ float tA[32][33], tB[32][33];
  int tx = threadIdx.x & 31, ty = threadIdx.x >> 5;
  int r0 = blockIdx.y * 32, c0 = blockIdx.x * 32;
  float inv = 1.0f / trIn[0];
  float acc[4] = {0.f, 0.f, 0.f, 0.f};
  for (int kt = 0; kt < 16; ++kt) {
    __syncthreads();
#pragma unroll
    for (int r = 0; r < 4; ++r) {
      tA[ty + r * 8][tx] = S[(size_t)(r0 + ty + r * 8) * DB + kt * 32 + tx];
      tB[ty + r * 8][tx] = S[(size_t)(kt * 32 + ty + r * 8) * DB + c0 + tx];
    }
    __syncthreads();
#pragma unroll
    for (int kk = 0; kk < 32; ++kk) {
      float b = tB[kk][tx];
#pragma unroll
      for (int r = 0; r < 4; ++r) acc[r] += tA[ty + r * 8][kk] * b;
    }
  }
  float inv2 = inv * inv;
#pragma unroll
  for (int r = 0; r < 4; ++r) {
    int row = r0 + ty + r * 8, col = c0 + tx;
    float v = acc[r] * inv2;
    D[(size_t)row * DB + col] = v;
    if (row == col) atomicAdd(trOut, v);
  }
}

__global__ void k_rayleigh(const float* __restrict__ Bm, const float* __restrict__ S,
                           float* __restrict__ slots) {
  int tid = blockIdx.x * 256 + threadIdx.x;
  float num = 0.f, den = 0.f;
  for (int i = tid; i < DB * DB; i += 256 * 256) {
    float s = S[i];
    num += Bm[i] * s;
    if ((i >> 9) == (i & 511)) den += s;
  }
  for (int off = 32; off > 0; off >>= 1) { num += __shfl_xor(num, off); den += __shfl_xor(den, off); }
  if ((threadIdx.x & 63) == 0) { atomicAdd(&slots[SL_NUM], num); atomicAdd(&slots[SL_DEN], den); }
}

__global__ void k_derive(float* slots, const float* __restrict__ Kp) {
  if (threadIdx.x == 0) {
    float cc = slots[SL_NUM] / slots[SL_DEN];
    slots[SL_C] = cc;
    float eta = 1.0f / cc;
    slots[SL_ETA] = eta;
    slots[SL_THR] = Kp[0] * eta;
  }
}

__global__ void k_norms(const float* __restrict__ slots, float* __restrict__ out) {
  int i = threadIdx.x;
  if (i < ITERS) out[i] = sqrtf(slots[SL_RES2 + i] / slots[SL_Y2]);
}

// ---------------- GEMM kernels (all barrier-free) ----------------
// B = Wn * Wn^T [512x512] row-major out, trace -> slots[SL_TR].
__global__ __launch_bounds__(256) void k_gemm_bbuild(const unsigned short* __restrict__ Wn_t,
                                                     float* __restrict__ Bm, float* __restrict__ slots) {
  accv_t acc[2][4];
  int w = threadIdx.x >> 6, lane = threadIdx.x & 63;
  int mt0 = blockIdx.y * 8 + w * 2, nt0 = blockIdx.x * 4;
  gemm_tt<2, 4, NB / 32>(Wn_t, NB / 16, Wn_t, NB / 16, mt0, nt0, acc);
  int l16 = lane & 15, quad = lane >> 4;
  float tr = 0.f;
#pragma unroll
  for (int mi = 0; mi < 2; ++mi)
#pragma unroll
    for (int ni = 0; ni < 4; ++ni) {
      int m = (mt0 + mi) * 16 + l16, nb = (nt0 + ni) * 16 + quad * 4;
      *(f4*)&Bm[(size_t)m * DB + nb] = acc[mi][ni];
#pragma unroll
      for (int r = 0; r < 4; ++r)
        if (m == nb + r) tr += acc[mi][ni][r];
    }
  if (tr != 0.f) atomicAdd(&slots[SL_TR], tr);
}

// Gamma0 = soft(eta*(Y@Wn), lam); Gh = Zh = Gamma0 (tiled).
// block 128x128, wave 64x64 (MI=4,NI=4), XCD-clustered grid 1024.
__global__ __launch_bounds__(256) void k_gemm_init(const unsigned short* __restrict__ Yh,
                                                   const unsigned short* __restrict__ Wt_t,
                                                   const float* __restrict__ slots,
                                                   const float* __restrict__ Kp,
                                                   unsigned short* __restrict__ Gh,
                                                   unsigned short* __restrict__ Zh) {
  accv_t acc[4][4];
  int w = threadIdx.x >> 6;
  int h = blockIdx.x;
  int xcd = h & 7, slot = h >> 3;            // 128 slots per XCD
  int band = xcd * 8 + (slot >> 4);          // 64 bands of 128 rows
  int nt = slot & 15;                        // 16 n-groups of 128 cols
  int mt0 = band * 8 + (w >> 1) * 4, nt0 = nt * 8 + (w & 1) * 4;
  gemm_tt<4, 4, DB / 32>(Yh, DB / 16, Wt_t, DB / 16, mt0, nt0, acc);
  float eta = slots[SL_ETA], lam = Kp[0];
#pragma unroll
  for (int mi = 0; mi < 4; ++mi)
#pragma unroll
    for (int ni = 0; ni < 4; ++ni) {
      size_t tb = ctile_off(mt0 + mi, nt0 + ni, NB / 16);
      us4 gq;
#pragma unroll
      for (int r = 0; r < 4; ++r) gq[r] = f2h(softthr(acc[mi][ni][r] * eta, lam));
      *(us4*)&Gh[tb] = gq;
      *(us4*)&Zh[tb] = gq;
    }
}

// Split-K=2 partial of R = Z @ Wn^T: fp32 tiled partials P (one per K-half).
// grid 1024 = 2 khalf x 512 XCD-clustered blocks; block 128m x 64n, wave 32x64.
__global__ __launch_bounds__(256) void k_gemm_res_part(const unsigned short* __restrict__ Zh,
                                                       const unsigned short* __restrict__ Wn_t,
                                                       float* __restrict__ P0,
                                                       float* __restrict__ P1) {
  accv_t acc[2][4];
  int w = threadIdx.x >> 6;
  int h = blockIdx.x;
  int khalf = h >> 9;                        // 0 or 1
  int hh = h & 511;
  int xcd = hh & 7, slot = hh >> 3;          // 64 slots per XCD
  int band = xcd * 8 + (slot >> 3);          // 64 bands of 128 rows
  int nt = slot & 7;                         // 8 n-groups of 64 cols
  int mt0 = band * 8 + w * 2, nt0 = nt * 4;
  const size_t koff = (size_t)khalf * 64 * 256;   // advance 64 k-tiles
  gemm_tt<2, 4, NB / 64>(Zh + koff, NB / 16, Wn_t + koff, NB / 16, mt0, nt0, acc);
  float* P = khalf ? P1 : P0;
#pragma unroll
  for (int mi = 0; mi < 2; ++mi)
#pragma unroll
    for (int ni = 0; ni < 4; ++ni) {
      size_t tb = ctile_off(mt0 + mi, nt0 + ni, DB / 16);
      *(f4*)&P[tb] = acc[mi][ni];
    }
}

// Rh = f2h(P0 + P1 - Y) (tiled, elementwise); ||R||^2 -> res2slot.
__global__ __launch_bounds__(256) void k_rescomb(const float* __restrict__ P0,
                                                 const float* __restrict__ P1,
                                                 const unsigned short* __restrict__ Yh,
                                                 unsigned short* __restrict__ Rh,
                                                 float* __restrict__ res2slot) {
  float s2 = 0.f;
  for (size_t u = (size_t)blockIdx.x * 256 + threadIdx.x; u < (size_t)(NR * DB / 4);
       u += (size_t)gridDim.x * 256) {
    f4 a = *(const f4*)&P0[u << 2];
    f4 b = *(const f4*)&P1[u << 2];
    us4 yq = *(const us4*)&Yh[u << 2];
    us4 rq;
#pragma unroll
    for (int r = 0; r < 4; ++r) {
      float rv = a[r] + b[r] - h2f(yq[r]);
      rq[r] = f2h(rv);
      s2 += rv * rv;
    }
    *(us4*)&Rh[u << 2] = rq;
  }
  for (int off = 32; off > 0; off >>= 1) s2 += __shfl_xor(s2, off);
  if ((threadIdx.x & 63) == 0) atomicAdd(res2slot, s2);
}

// Fallback single-kernel res (round-4 exact), used if ws too small for partials.
__global__ __launch_bounds__(256) void k_gemm_res(const unsigned short* __restrict__ Zh,
                                                  const unsigned short* __restrict__ Wn_t,
                                                  const unsigned short* __restrict__ Yh,
                                                  unsigned short* __restrict__ Rh,
                                                  float* __restrict__ res2slot) {
  accv_t acc[2][4];
  int w = threadIdx.x >> 6;
  int h = blockIdx.x;
  int xcd = h & 7, slot = h >> 3;
  int band = xcd * 8 + (slot >> 3);
  int nt = slot & 7;
  int mt0 = band * 8 + w * 2, nt0 = nt * 4;
  gemm_tt<2, 4, NB / 32>(Zh, NB / 16, Wn_t, NB / 16, mt0, nt0, acc);
  float s2 = 0.f;
#pragma unroll
  for (int mi = 0; mi < 2; ++mi)
#pragma unroll
    for (int ni = 0; ni < 4; ++ni) {
      size_t tb = ctile_off(mt0 + mi, nt0 + ni, DB / 16);
      us4 yq = *(const us4*)&Yh[tb];
      us4 rq;
#pragma unroll
      for (int r = 0; r < 4; ++r) {
        float rv = acc[mi][ni][r] - h2f(yq[r]);
        rq[r] = f2h(rv);
        s2 += rv * rv;
      }
      *(us4*)&Rh[tb] = rq;
    }
  for (int off = 32; off > 0; off >>= 1) s2 += __shfl_xor(s2, off);
  if ((threadIdx.x & 63) == 0) atomicAdd(res2slot, s2);
}

// G = R @ Wn ; gn = soft(Z - eta*G, lam/c); Z = gn + mom*(gn-Gamma_old); Gh = gn.
// block 128x128, wave 64x64 (MI=4,NI=4), XCD-clustered grid 1024.
__global__ __launch_bounds__(256) void k_gemm_upd(const unsigned short* __restrict__ Rh,
                                                  const unsigned short* __restrict__ Wt_t,
                                                  const float* __restrict__ slots,
                                                  unsigned short* __restrict__ Gh,
                                                  unsigned short* __restrict__ Zh,
                                                  float* __restrict__ GammaOut,
                                                  float mom, int writeFinal) {
  accv_t acc[4][4];
  int w = threadIdx.x >> 6, lane = threadIdx.x & 63;
  int h = blockIdx.x;
  int xcd = h & 7, slot = h >> 3;            // 128 slots per XCD
  int band = xcd * 8 + (slot >> 4);          // 64 bands of 128 rows
  int nt = slot & 15;                        // 16 n-groups of 128 cols
  int mt0 = band * 8 + (w >> 1) * 4, nt0 = nt * 8 + (w & 1) * 4;
  gemm_tt<4, 4, DB / 32>(Rh, DB / 16, Wt_t, DB / 16, mt0, nt0, acc);
  int l16 = lane & 15, quad = lane >> 4;
  float eta = slots[SL_ETA], thr = slots[SL_THR];
#pragma unroll
  for (int mi = 0; mi < 4; ++mi)
#pragma unroll
    for (int ni = 0; ni < 4; ++ni) {
      size_t tb = ctile_off(mt0 + mi, nt0 + ni, NB / 16);
      us4 zq = *(const us4*)&Zh[tb];
      us4 gq = *(const us4*)&Gh[tb];
      us4 gho, zho;
      f4 gf;
#pragma unroll
      for (int r = 0; r < 4; ++r) {
        float z = h2f(zq[r]);
        float gold = h2f(gq[r]);
        float gn = softthr(z - eta * acc[mi][ni][r], thr);
        float zn = gn + mom * (gn - gold);
        gho[r] = f2h(gn);
        zho[r] = f2h(zn);
        gf[r] = gn;
      }
      *(us4*)&Gh[tb] = gho;
      *(us4*)&Zh[tb] = zho;
      if (writeFinal) {
        int m = (mt0 + mi) * 16 + l16, nb = (nt0 + ni) * 16 + quad * 4;
        *(f4*)&GammaOut[(size_t)m * NB + nb] = gf;
      }
    }
}

// X = Gamma @ Wn^T (row-major fp32 out). block 128m x 64n, XCD-clustered grid 512.
__global__ __launch_bounds__(256) void k_gemm_x(const unsigned short* __restrict__ Gh,
                                                const unsigned short* __restrict__ Wn_t,
                                                float* __restrict__ X) {
  accv_t acc[2][4];
  int w = threadIdx.x >> 6, lane = threadIdx.x & 63;
  int h = blockIdx.x;
  int xcd = h & 7, slot = h >> 3;
  int band = xcd * 8 + (slot >> 3);
  int nt = slot & 7;
  int mt0 = band * 8 + w * 2, nt0 = nt * 4;
  gemm_tt<2, 4, NB / 32>(Gh, NB / 16, Wn_t, NB / 16, mt0, nt0, acc);
  int l16 = lane & 15, quad = lane >> 4;
#pragma unroll
  for (int mi = 0; mi < 2; ++mi)
#pragma unroll
    for (int ni = 0; ni < 4; ++ni) {
      int m = (mt0 + mi) * 16 + l16, nb = (nt0 + ni) * 16 + quad * 4;
      *(f4*)&X[(size_t)m * DB + nb] = acc[mi][ni];
    }
}

extern "C" void kernel_launch(void* const* d_in, const int* in_sizes, int n_in,
                              void* d_out, int out_size, void* d_ws, size_t ws_size,
                              hipStream_t stream) {
  const float* Y  = (const float*)d_in[0];
  const float* W  = (const float*)d_in[1];
  const float* Kp = (const float*)d_in[2];

  float* Xout     = (float*)d_out;
  float* GammaOut = Xout + (size_t)NR * DB;
  float* NormsOut = GammaOut + (size_t)NR * NB;

  char* p = (char*)d_ws;
  auto carve = [&](size_t bytes) -> void* {
    void* r = (void*)p; p += (bytes + 255) & ~(size_t)255; return r;
  };
  float* slots = (float*)carve(64 * 4);
  float* colsq = (float*)carve(NB * 4);
  float* Bmat  = (float*)carve((size_t)DB * DB * 4);
  float* S0    = (float*)carve((size_t)DB * DB * 4);
  float* S1    = (float*)carve((size_t)DB * DB * 4);
  unsigned short* Wn_t = (unsigned short*)carve((size_t)DB * NB * 2);
  unsigned short* Wt_t = (unsigned short*)carve((size_t)NB * DB * 2);
  unsigned short* Yh   = (unsigned short*)carve((size_t)NR * DB * 2);
  unsigned short* Rh   = (unsigned short*)carve((size_t)NR * DB * 2);
  unsigned short* Zh   = (unsigned short*)carve((size_t)NR * NB * 2);
  unsigned short* Gh   = (unsigned short*)carve((size_t)NR * NB * 2);
  float* P0 = (float*)carve((size_t)NR * DB * 4);
  float* P1 = (float*)carve((size_t)NR * DB * 4);
  const bool splitk = ((size_t)(p - (char*)d_ws) <= ws_size);

  k_zero<<<1, 256, 0, stream>>>(slots, colsq);
  k_colsq<<<dim3(NB / 256, DB / 64), 256, 0, stream>>>(W, colsq);
  k_wnorm<<<dim3(NB / 32, DB / 32), 256, 0, stream>>>(W, colsq, Wn_t, Wt_t);
  k_ynorm<<<512, 256, 0, stream>>>(Y, Yh, slots);

  // power method replacement: B = Wn Wn^T, then 9 trace-normalized squarings + Rayleigh
  k_gemm_bbuild<<<dim3(DB / 64, DB / 128), 256, 0, stream>>>(Wn_t, Bmat, slots);
  float* ss[2] = {S0, S1};
  for (int k = 0; k < NSQ; ++k) {
    const float* in = (k == 0) ? Bmat : ss[(k + 1) & 1];
    k_sq<<<dim3(16, 16), 256, 0, stream>>>(in, ss[k & 1], slots + SL_TR + k, slots + SL_TR + k + 1);
  }
  k_rayleigh<<<256, 256, 0, stream>>>(Bmat, ss[(NSQ + 1) & 1], slots);
  k_derive<<<1, 64, 0, stream>>>(slots, Kp);

  // FISTA
  k_gemm_init<<<1024, 256, 0, stream>>>(Yh, Wt_t, slots, Kp, Gh, Zh);
  double t = 1.0;
  for (int i = 0; i < ITERS; ++i) {
    if (splitk) {
      k_gemm_res_part<<<1024, 256, 0, stream>>>(Zh, Wn_t, P0, P1);
      k_rescomb<<<1024, 256, 0, stream>>>(P0, P1, Yh, Rh, slots + SL_RES2 + i);
    } else {
      k_gemm_res<<<512, 256, 0, stream>>>(Zh, Wn_t, Yh, Rh, slots + SL_RES2 + i);
    }
    double tn = (1.0 + sqrt(1.0 + 4.0 * t * t)) / 2.0;
    float mom = (float)((t - 1.0) / tn);
    t = tn;
    k_gemm_upd<<<1024, 256, 0, stream>>>(Rh, Wt_t, slots, Gh, Zh, GammaOut,
                                         mom, (i == ITERS - 1) ? 1 : 0);
  }
  k_gemm_x<<<512, 256, 0, stream>>>(Gh, Wn_t, Xout);
  k_norms<<<1, 64, 0, stream>>>(slots, NormsOut);
}

// Round 7
// 2422.017 us; speedup vs baseline: 1.3686x; 1.3686x over previous
//
#include <hip/hip_runtime.h>
#include <cmath>

#define NR   8192   // rows of Y
#define DB   512    // signal dim n
#define NB   2048   // dictionary atoms m
#define ITERS 20
#define NSQ   9     // trace-normalized squarings of B

typedef _Float16 hfrag_t __attribute__((ext_vector_type(8)));  // 8 fp16 = 16B
typedef __attribute__((ext_vector_type(4))) float accv_t;      // 4 fp32
typedef unsigned short us4 __attribute__((ext_vector_type(4))); // 8B
typedef unsigned short us8 __attribute__((ext_vector_type(8))); // 16B
typedef float f4 __attribute__((ext_vector_type(4)));           // 16B

// scalar slots in ws
#define SL_Y2   0
#define SL_NUM  1
#define SL_DEN  2
#define SL_C    3
#define SL_ETA  4
#define SL_THR  5
#define SL_TR   6    // 6..15  traces
#define SL_RES2 16   // 16..35 per-iter ||R||^2

__device__ inline unsigned short f2h(float f) {
  _Float16 h = (_Float16)f;
  return __builtin_bit_cast(unsigned short, h);
}
__device__ inline float h2f(unsigned short u) {
  _Float16 h = __builtin_bit_cast(_Float16, u);
  return (float)h;
}
__device__ inline float softthr(float x, float t) {
  float a = fabsf(x) - t;
  return a > 0.f ? copysignf(a, x) : 0.f;
}

// ---- Fragment-native tiled layout ----
// 16x16 tile = 256 contiguous fp16, element (m,k) at m*16+k (row-major in tile).
// A-fragment for mfma_16x16x32 (operand-swapped): lane (l16,quad) needs
// A[m=l16][k=quad*8+j] j=0..7 -> tile kt*2+(quad>>1), bytes l16*32+(quad&1)*16:
// ONE 16B load per fragment; wave covers 512B contiguous. Same for B (n,k).
// C tile: lane owns (m=l16, n=quad*4+r) -> us4 at byte l16*32+quad*8.

// ---- barrier-free MFMA GEMM core: both operands tiled, no LDS ----
// EXACT round-0 proven text. Do NOT restructure (lambda/UNR/manual-PF all
// regressed in r1/r5/r6). Register budget is controlled ONLY via the callers'
// __launch_bounds__.
template<int MI, int NI, int NKT>
__device__ inline void gemm_tt(const unsigned short* __restrict__ At, int NTka,
                               const unsigned short* __restrict__ Bt, int NTkb,
                               int mt0, int nt0, accv_t acc[MI][NI]) {
  const int lane = threadIdx.x & 63;
  const int l16 = lane & 15, quad = lane >> 4;
  const int off = l16 * 16 + (quad & 1) * 8;   // element offset within tile
  const int kh = quad >> 1;
#pragma unroll
  for (int mi = 0; mi < MI; ++mi)
#pragma unroll
    for (int ni = 0; ni < NI; ++ni) acc[mi][ni] = (accv_t){0.f, 0.f, 0.f, 0.f};

#pragma unroll 4
  for (int kt = 0; kt < NKT; ++kt) {
    const int ktile = (kt << 1) + kh;
    hfrag_t af[MI], bf[NI];
#pragma unroll
    for (int mi = 0; mi < MI; ++mi)
      af[mi] = *(const hfrag_t*)&At[(((size_t)(mt0 + mi) * NTka + ktile) << 8) + off];
#pragma unroll
    for (int ni = 0; ni < NI; ++ni)
      bf[ni] = *(const hfrag_t*)&Bt[(((size_t)(nt0 + ni) * NTkb + ktile) << 8) + off];
#pragma unroll
    for (int mi = 0; mi < MI; ++mi)
#pragma unroll
      for (int ni = 0; ni < NI; ++ni)
        acc[mi][ni] = __builtin_amdgcn_mfma_f32_16x16x32_f16(bf[ni], af[mi], acc[mi][ni], 0, 0, 0);
  }
}

// C-tile epilogue offset (element units) for tiled fp16 surfaces
__device__ inline size_t ctile_off(int mt, int nt, int NTn) {
  int lane = threadIdx.x & 63;
  return (((size_t)mt * NTn + nt) << 8) + (lane & 15) * 16 + (lane >> 4) * 4;
}

// ---------------- small kernels ----------------
__global__ void k_zero(float* slots, float* colsq) {
  if (threadIdx.x < 64) slots[threadIdx.x] = 0.f;
  for (int i = threadIdx.x; i < NB; i += 256) colsq[i] = 0.f;
}

// column sum-of-squares, row-split partials (grid (8 colgroups, 8 rowgroups))
__global__ void k_colsq(const float* __restrict__ W, float* __restrict__ colsq) {
  int j = blockIdx.x * 256 + threadIdx.x;     // column
  int r0 = blockIdx.y * 64;
  float s = 0.f;
  for (int i = 0; i < 64; ++i) { float v = W[(size_t)(r0 + i) * NB + j]; s += v * v; }
  atomicAdd(&colsq[j], s);
}

// normalize cols; emit tiled Wn_t [DB/16][NB/16] (elem (i,j)->i*16+j)
// and tiled Wt_t [NB/16][DB/16] (elem (j,i)->j*16+i)
__global__ void k_wnorm(const float* __restrict__ W, const float* __restrict__ colsq,
                        unsigned short* __restrict__ Wn_t, unsigned short* __restrict__ Wt_t) {
  int tx = threadIdx.x & 31, ty = threadIdx.x >> 5;
  int j = blockIdx.x * 32 + tx;               // NB index
  float inv = 1.0f / sqrtf(colsq[j]);
#pragma unroll
  for (int r = 0; r < 4; ++r) {
    int i = blockIdx.y * 32 + ty + r * 8;     // DB index
    unsigned short h = f2h(W[(size_t)i * NB + j] * inv);
    Wn_t[(((size_t)(i >> 4) * (NB / 16) + (j >> 4)) << 8) + (i & 15) * 16 + (j & 15)] = h;
    Wt_t[(((size_t)(j >> 4) * (DB / 16) + (i >> 4)) << 8) + (j & 15) * 16 + (i & 15)] = h;
  }
}

// Y (row-major fp32) -> Yh (tiled fp16) + ||Y||^2.
// Wave-per-row: fully coalesced 2KB reads; one atomic per block.
__global__ __launch_bounds__(256) void k_ynorm(const float* __restrict__ Y,
                                               unsigned short* __restrict__ Yh,
                                               float* __restrict__ slots) {
  __shared__ float part[4];
  int w = threadIdx.x >> 6, lane = threadIdx.x & 63;
  float s = 0.f;
#pragma unroll
  for (int rr = 0; rr < 4; ++rr) {
    int m = blockIdx.x * 16 + w * 4 + rr;     // 512 blocks x 16 rows
    const float* yrow = &Y[(size_t)m * DB + lane * 8];
    f4 v0 = *(const f4*)yrow;
    f4 v1 = *(const f4*)(yrow + 4);
    us8 h;
#pragma unroll
    for (int q = 0; q < 4; ++q) {
      h[q] = f2h(v0[q]);     s += v0[q] * v0[q];
      h[4 + q] = f2h(v1[q]); s += v1[q] * v1[q];
    }
    *(us8*)&Yh[(((size_t)(m >> 4) * 32 + (lane >> 1)) << 8) + (m & 15) * 16 + (lane & 1) * 8] = h;
  }
  for (int off = 32; off > 0; off >>= 1) s += __shfl_xor(s, off);
  if (lane == 0) part[w] = s;
  __syncthreads();
  if (threadIdx.x == 0) atomicAdd(&slots[SL_Y2], part[0] + part[1] + part[2] + part[3]);
}

// fp32 squaring: D = (S/tr)^2, accumulate trace(D)
__global__ __launch_bounds__(256) void k_sq(const float* __restrict__ S, float* __restrict__ D,
                                            const float* __restrict__ trIn, float* __restrict__ trOut) {
  __shared__ float tA[32][33], tB[32][33];
  int tx = threadIdx.x & 31, ty = threadIdx.x >> 5;
  int r0 = blockIdx.y * 32, c0 = blockIdx.x * 32;
  float inv = 1.0f / trIn[0];
  float acc[4] = {0.f, 0.f, 0.f, 0.f};
  for (int kt = 0; kt < 16; ++kt) {
    __syncthreads();
#pragma unroll
    for (int r = 0; r < 4; ++r) {
      tA[ty + r * 8][tx] = S[(size_t)(r0 + ty + r * 8) * DB + kt * 32 + tx];
      tB[ty + r * 8][tx] = S[(size_t)(kt * 32 + ty + r * 8) * DB + c0 + tx];
    }
    __syncthreads();
#pragma unroll
    for (int kk = 0; kk < 32; ++kk) {
      float b = tB[kk][tx];
#pragma unroll
      for (int r = 0; r < 4; ++r) acc[r] += tA[ty + r * 8][kk] * b;
    }
  }
  float inv2 = inv * inv;
#pragma unroll
  for (int r = 0; r < 4; ++r) {
    int row = r0 + ty + r * 8, col = c0 + tx;
    float v = acc[r] * inv2;
    D[(size_t)row * DB + col] = v;
    if (row == col) atomicAdd(trOut, v);
  }
}

__global__ void k_rayleigh(const float* __restrict__ Bm, const float* __restrict__ S,
                           float* __restrict__ slots) {
  int tid = blockIdx.x * 256 + threadIdx.x;
  float num = 0.f, den = 0.f;
  for (int i = tid; i < DB * DB; i += 256 * 256) {
    float s = S[i];
    num += Bm[i] * s;
    if ((i >> 9) == (i & 511)) den += s;
  }
  for (int off = 32; off > 0; off >>= 1) { num += __shfl_xor(num, off); den += __shfl_xor(den, off); }
  if ((threadIdx.x & 63) == 0) { atomicAdd(&slots[SL_NUM], num); atomicAdd(&slots[SL_DEN], den); }
}

__global__ void k_derive(float* slots, const float* __restrict__ Kp) {
  if (threadIdx.x == 0) {
    float cc = slots[SL_NUM] / slots[SL_DEN];
    slots[SL_C] = cc;
    float eta = 1.0f / cc;
    slots[SL_ETA] = eta;
    slots[SL_THR] = Kp[0] * eta;
  }
}

__global__ void k_norms(const float* __restrict__ slots, float* __restrict__ out) {
  int i = threadIdx.x;
  if (i < ITERS) out[i] = sqrtf(slots[SL_RES2 + i] / slots[SL_Y2]);
}

// ---------------- GEMM kernels (all barrier-free) ----------------
// B = Wn * Wn^T [512x512] row-major out, trace -> slots[SL_TR].
// Grid 32 blocks (tiny) -> register budget free: launch_bounds(256,1).
__global__ __launch_bounds__(256, 1) void k_gemm_bbuild(const unsigned short* __restrict__ Wn_t,
                                                        float* __restrict__ Bm, float* __restrict__ slots) {
  accv_t acc[2][4];
  int w = threadIdx.x >> 6, lane = threadIdx.x & 63;
  int mt0 = blockIdx.y * 8 + w * 2, nt0 = blockIdx.x * 4;
  gemm_tt<2, 4, NB / 32>(Wn_t, NB / 16, Wn_t, NB / 16, mt0, nt0, acc);
  int l16 = lane & 15, quad = lane >> 4;
  float tr = 0.f;
#pragma unroll
  for (int mi = 0; mi < 2; ++mi)
#pragma unroll
    for (int ni = 0; ni < 4; ++ni) {
      int m = (mt0 + mi) * 16 + l16, nb = (nt0 + ni) * 16 + quad * 4;
      *(f4*)&Bm[(size_t)m * DB + nb] = acc[mi][ni];
#pragma unroll
      for (int r = 0; r < 4; ++r)
        if (m == nb + r) tr += acc[mi][ni][r];
    }
  if (tr != 0.f) atomicAdd(&slots[SL_TR], tr);
}

// Gamma0 = soft(eta*(Y@Wn), lam); Gh = Zh = Gamma0 (tiled).
// block 128x128, wave 64x64 (MI=4,NI=4), XCD-clustered grid 1024. (proven form)
__global__ __launch_bounds__(256) void k_gemm_init(const unsigned short* __restrict__ Yh,
                                                   const unsigned short* __restrict__ Wt_t,
                                                   const float* __restrict__ slots,
                                                   const float* __restrict__ Kp,
                                                   unsigned short* __restrict__ Gh,
                                                   unsigned short* __restrict__ Zh) {
  accv_t acc[4][4];
  int w = threadIdx.x >> 6;
  int h = blockIdx.x;
  int xcd = h & 7, slot = h >> 3;            // 128 slots per XCD
  int band = xcd * 8 + (slot >> 4);          // 64 bands of 128 rows
  int nt = slot & 15;                        // 16 n-groups of 128 cols
  int mt0 = band * 8 + (w >> 1) * 4, nt0 = nt * 8 + (w & 1) * 4;
  gemm_tt<4, 4, DB / 32>(Yh, DB / 16, Wt_t, DB / 16, mt0, nt0, acc);
  float eta = slots[SL_ETA], lam = Kp[0];
#pragma unroll
  for (int mi = 0; mi < 4; ++mi)
#pragma unroll
    for (int ni = 0; ni < 4; ++ni) {
      size_t tb = ctile_off(mt0 + mi, nt0 + ni, NB / 16);
      us4 gq;
#pragma unroll
      for (int r = 0; r < 4; ++r) gq[r] = f2h(softthr(acc[mi][ni][r] * eta, lam));
      *(us4*)&Gh[tb] = gq;
      *(us4*)&Zh[tb] = gq;
    }
}

// R = Z @ Wn^T - Y (tiled); ||R||^2.
// block 128m x 64n, wave 32x64 (MI=2,NI=4), XCD-clustered grid 512.
// Grid caps occupancy at 2 waves/SIMD -> launch_bounds(256,1) frees the
// register budget (up to 256 VGPR keeps 2/SIMD) so the unroll-4 window's
// 24 fragment loads can stay in flight. Loop text unchanged (r1/r5 lesson).
__global__ __launch_bounds__(256, 1) void k_gemm_res(const unsigned short* __restrict__ Zh,
                                                     const unsigned short* __restrict__ Wn_t,
                                                     const unsigned short* __restrict__ Yh,
                                                     unsigned short* __restrict__ Rh,
                                                     float* __restrict__ res2slot) {
  accv_t acc[2][4];
  int w = threadIdx.x >> 6;
  int h = blockIdx.x;
  int xcd = h & 7, slot = h >> 3;            // 64 slots per XCD
  int band = xcd * 8 + (slot >> 3);          // 64 bands of 128 rows
  int nt = slot & 7;                         // 8 n-groups of 64 cols
  int mt0 = band * 8 + w * 2, nt0 = nt * 4;
  gemm_tt<2, 4, NB / 32>(Zh, NB / 16, Wn_t, NB / 16, mt0, nt0, acc);
  float s2 = 0.f;
#pragma unroll
  for (int mi = 0; mi < 2; ++mi)
#pragma unroll
    for (int ni = 0; ni < 4; ++ni) {
      size_t tb = ctile_off(mt0 + mi, nt0 + ni, DB / 16);
      us4 yq = *(const us4*)&Yh[tb];
      us4 rq;
#pragma unroll
      for (int r = 0; r < 4; ++r) {
        float rv = acc[mi][ni][r] - h2f(yq[r]);
        rq[r] = f2h(rv);
        s2 += rv * rv;
      }
      *(us4*)&Rh[tb] = rq;
    }
  for (int off = 32; off > 0; off >>= 1) s2 += __shfl_xor(s2, off);
  if ((threadIdx.x & 63) == 0) atomicAdd(res2slot, s2);
}

// G = R @ Wn ; gn = soft(Z - eta*G, lam/c); Z = gn + mom*(gn-Gamma_old); Gh = gn.
// block 128x128, wave 64x64 (MI=4,NI=4), XCD-clustered grid 1024. (proven form;
// VGPR 92-96 exactly fits its 4 waves/SIMD grid demand -> do not touch)
__global__ __launch_bounds__(256) void k_gemm_upd(const unsigned short* __restrict__ Rh,
                                                  const unsigned short* __restrict__ Wt_t,
                                                  const float* __restrict__ slots,
                                                  unsigned short* __restrict__ Gh,
                                                  unsigned short* __restrict__ Zh,
                                                  float* __restrict__ GammaOut,
                                                  float mom, int writeFinal) {
  accv_t acc[4][4];
  int w = threadIdx.x >> 6, lane = threadIdx.x & 63;
  int h = blockIdx.x;
  int xcd = h & 7, slot = h >> 3;            // 128 slots per XCD
  int band = xcd * 8 + (slot >> 4);          // 64 bands of 128 rows
  int nt = slot & 15;                        // 16 n-groups of 128 cols
  int mt0 = band * 8 + (w >> 1) * 4, nt0 = nt * 8 + (w & 1) * 4;
  gemm_tt<4, 4, DB / 32>(Rh, DB / 16, Wt_t, DB / 16, mt0, nt0, acc);
  int l16 = lane & 15, quad = lane >> 4;
  float eta = slots[SL_ETA], thr = slots[SL_THR];
#pragma unroll
  for (int mi = 0; mi < 4; ++mi)
#pragma unroll
    for (int ni = 0; ni < 4; ++ni) {
      size_t tb = ctile_off(mt0 + mi, nt0 + ni, NB / 16);
      us4 zq = *(const us4*)&Zh[tb];
      us4 gq = *(const us4*)&Gh[tb];
      us4 gho, zho;
      f4 gf;
#pragma unroll
      for (int r = 0; r < 4; ++r) {
        float z = h2f(zq[r]);
        float gold = h2f(gq[r]);
        float gn = softthr(z - eta * acc[mi][ni][r], thr);
        float zn = gn + mom * (gn - gold);
        gho[r] = f2h(gn);
        zho[r] = f2h(zn);
        gf[r] = gn;
      }
      *(us4*)&Gh[tb] = gho;
      *(us4*)&Zh[tb] = zho;
      if (writeFinal) {
        int m = (mt0 + mi) * 16 + l16, nb = (nt0 + ni) * 16 + quad * 4;
        *(f4*)&GammaOut[(size_t)m * NB + nb] = gf;
      }
    }
}

// X = Gamma @ Wn^T (row-major fp32 out).
// block 128m x 64n, XCD-clustered grid 512; grid-capped -> launch_bounds(256,1).
__global__ __launch_bounds__(256, 1) void k_gemm_x(const unsigned short* __restrict__ Gh,
                                                   const unsigned short* __restrict__ Wn_t,
                                                   float* __restrict__ X) {
  accv_t acc[2][4];
  int w = threadIdx.x >> 6, lane = threadIdx.x & 63;
  int h = blockIdx.x;
  int xcd = h & 7, slot = h >> 3;
  int band = xcd * 8 + (slot >> 3);
  int nt = slot & 7;
  int mt0 = band * 8 + w * 2, nt0 = nt * 4;
  gemm_tt<2, 4, NB / 32>(Gh, NB / 16, Wn_t, NB / 16, mt0, nt0, acc);
  int l16 = lane & 15, quad = lane >> 4;
#pragma unroll
  for (int mi = 0; mi < 2; ++mi)
#pragma unroll
    for (int ni = 0; ni < 4; ++ni) {
      int m = (mt0 + mi) * 16 + l16, nb = (nt0 + ni) * 16 + quad * 4;
      *(f4*)&X[(size_t)m * DB + nb] = acc[mi][ni];
    }
}

extern "C" void kernel_launch(void* const* d_in, const int* in_sizes, int n_in,
                              void* d_out, int out_size, void* d_ws, size_t ws_size,
                              hipStream_t stream) {
  const float* Y  = (const float*)d_in[0];
  const float* W  = (const float*)d_in[1];
  const float* Kp = (const float*)d_in[2];

  float* Xout     = (float*)d_out;
  float* GammaOut = Xout + (size_t)NR * DB;
  float* NormsOut = GammaOut + (size_t)NR * NB;

  char* p = (char*)d_ws;
  auto carve = [&](size_t bytes) -> void* {
    void* r = (void*)p; p += (bytes + 255) & ~(size_t)255; return r;
  };
  float* slots = (float*)carve(64 * 4);
  float* colsq = (float*)carve(NB * 4);
  float* Bmat  = (float*)carve((size_t)DB * DB * 4);
  float* S0    = (float*)carve((size_t)DB * DB * 4);
  float* S1    = (float*)carve((size_t)DB * DB * 4);
  unsigned short* Wn_t = (unsigned short*)carve((size_t)DB * NB * 2);
  unsigned short* Wt_t = (unsigned short*)carve((size_t)NB * DB * 2);
  unsigned short* Yh   = (unsigned short*)carve((size_t)NR * DB * 2);
  unsigned short* Rh   = (unsigned short*)carve((size_t)NR * DB * 2);
  unsigned short* Zh   = (unsigned short*)carve((size_t)NR * NB * 2);
  unsigned short* Gh   = (unsigned short*)carve((size_t)NR * NB * 2);

  k_zero<<<1, 256, 0, stream>>>(slots, colsq);
  k_colsq<<<dim3(NB / 256, DB / 64), 256, 0, stream>>>(W, colsq);
  k_wnorm<<<dim3(NB / 32, DB / 32), 256, 0, stream>>>(W, colsq, Wn_t, Wt_t);
  k_ynorm<<<512, 256, 0, stream>>>(Y, Yh, slots);

  // power method replacement: B = Wn Wn^T, then 9 trace-normalized squarings + Rayleigh
  k_gemm_bbuild<<<dim3(DB / 64, DB / 128), 256, 0, stream>>>(Wn_t, Bmat, slots);
  float* ss[2] = {S0, S1};
  for (int k = 0; k < NSQ; ++k) {
    const float* in = (k == 0) ? Bmat : ss[(k + 1) & 1];
    k_sq<<<dim3(16, 16), 256, 0, stream>>>(in, ss[k & 1], slots + SL_TR + k, slots + SL_TR + k + 1);
  }
  k_rayleigh<<<256, 256, 0, stream>>>(Bmat, ss[(NSQ + 1) & 1], slots);
  k_derive<<<1, 64, 0, stream>>>(slots, Kp);

  // FISTA
  k_gemm_init<<<1024, 256, 0, stream>>>(Yh, Wt_t, slots, Kp, Gh, Zh);
  double t = 1.0;
  for (int i = 0; i < ITERS; ++i) {
    k_gemm_res<<<512, 256, 0, stream>>>(Zh, Wn_t, Yh, Rh, slots + SL_RES2 + i);
    double tn = (1.0 + sqrt(1.0 + 4.0 * t * t)) / 2.0;
    float mom = (float)((t - 1.0) / tn);
    t = tn;
    k_gemm_upd<<<1024, 256, 0, stream>>>(Rh, Wt_t, slots, Gh, Zh, GammaOut,
                                         mom, (i == ITERS - 1) ? 1 : 0);
  }
  k_gemm_x<<<512, 256, 0, stream>>>(Gh, Wn_t, Xout);
  k_norms<<<1, 64, 0, stream>>>(slots, NormsOut);
}

// Round 8
// 2391.745 us; speedup vs baseline: 1.3860x; 1.0127x over previous
//
#include <hip/hip_runtime.h>
#include <cmath>

#define NR   8192   // rows of Y
#define DB   512    // signal dim n
#define NB   2048   // dictionary atoms m
#define ITERS 20
#define NSQ   9     // trace-normalized squarings of B

typedef _Float16 hfrag_t __attribute__((ext_vector_type(8)));  // 8 fp16 = 16B
typedef __attribute__((ext_vector_type(4))) float accv_t;      // 4 fp32
typedef unsigned short us4 __attribute__((ext_vector_type(4))); // 8B
typedef unsigned short us8 __attribute__((ext_vector_type(8))); // 16B
typedef float f4 __attribute__((ext_vector_type(4)));           // 16B

// scalar slots in ws
#define SL_Y2   0
#define SL_NUM  1
#define SL_DEN  2
#define SL_C    3
#define SL_ETA  4
#define SL_THR  5
#define SL_TR   6    // 6..15  traces
#define SL_RES2 16   // 16..35 per-iter ||R||^2

__device__ inline unsigned short f2h(float f) {
  _Float16 h = (_Float16)f;
  return __builtin_bit_cast(unsigned short, h);
}
__device__ inline float h2f(unsigned short u) {
  _Float16 h = __builtin_bit_cast(_Float16, u);
  return (float)h;
}
__device__ inline float softthr(float x, float t) {
  float a = fabsf(x) - t;
  return a > 0.f ? copysignf(a, x) : 0.f;
}

// ---- Fragment-native tiled layout ----
// 16x16 tile = 256 contiguous fp16, element (m,k) at m*16+k (row-major in tile).
// A-fragment for mfma_16x16x32 (operand-swapped): lane (l16,quad) needs
// A[m=l16][k=quad*8+j] j=0..7 -> tile kt*2+(quad>>1), bytes l16*32+(quad&1)*16:
// ONE 16B load per fragment; wave covers 512B contiguous. Same for B (n,k).
// C tile: lane owns (m=l16, n=quad*4+r) -> us4 at byte l16*32+quad*8.

// ---- barrier-free MFMA GEMM core: both operands tiled, no LDS ----
// EXACT round-0 proven text. Do NOT restructure (lambda/UNR/manual-PF all
// regressed in r1/r5/r6).
template<int MI, int NI, int NKT>
__device__ inline void gemm_tt(const unsigned short* __restrict__ At, int NTka,
                               const unsigned short* __restrict__ Bt, int NTkb,
                               int mt0, int nt0, accv_t acc[MI][NI]) {
  const int lane = threadIdx.x & 63;
  const int l16 = lane & 15, quad = lane >> 4;
  const int off = l16 * 16 + (quad & 1) * 8;   // element offset within tile
  const int kh = quad >> 1;
#pragma unroll
  for (int mi = 0; mi < MI; ++mi)
#pragma unroll
    for (int ni = 0; ni < NI; ++ni) acc[mi][ni] = (accv_t){0.f, 0.f, 0.f, 0.f};

#pragma unroll 4
  for (int kt = 0; kt < NKT; ++kt) {
    const int ktile = (kt << 1) + kh;
    hfrag_t af[MI], bf[NI];
#pragma unroll
    for (int mi = 0; mi < MI; ++mi)
      af[mi] = *(const hfrag_t*)&At[(((size_t)(mt0 + mi) * NTka + ktile) << 8) + off];
#pragma unroll
    for (int ni = 0; ni < NI; ++ni)
      bf[ni] = *(const hfrag_t*)&Bt[(((size_t)(nt0 + ni) * NTkb + ktile) << 8) + off];
#pragma unroll
    for (int mi = 0; mi < MI; ++mi)
#pragma unroll
      for (int ni = 0; ni < NI; ++ni)
        acc[mi][ni] = __builtin_amdgcn_mfma_f32_16x16x32_f16(bf[ni], af[mi], acc[mi][ni], 0, 0, 0);
  }
}

// C-tile epilogue offset (element units) for tiled fp16 surfaces
__device__ inline size_t ctile_off(int mt, int nt, int NTn) {
  int lane = threadIdx.x & 63;
  return (((size_t)mt * NTn + nt) << 8) + (lane & 15) * 16 + (lane >> 4) * 4;
}

// ---------------- small kernels ----------------
__global__ void k_zero(float* slots, float* colsq) {
  if (threadIdx.x < 64) slots[threadIdx.x] = 0.f;
  for (int i = threadIdx.x; i < NB; i += 256) colsq[i] = 0.f;
}

// column sum-of-squares, row-split partials (grid (8 colgroups, 8 rowgroups))
__global__ void k_colsq(const float* __restrict__ W, float* __restrict__ colsq) {
  int j = blockIdx.x * 256 + threadIdx.x;     // column
  int r0 = blockIdx.y * 64;
  float s = 0.f;
  for (int i = 0; i < 64; ++i) { float v = W[(size_t)(r0 + i) * NB + j]; s += v * v; }
  atomicAdd(&colsq[j], s);
}

// normalize cols; emit tiled Wn_t [DB/16][NB/16] (elem (i,j)->i*16+j)
// and tiled Wt_t [NB/16][DB/16] (elem (j,i)->j*16+i)
__global__ void k_wnorm(const float* __restrict__ W, const float* __restrict__ colsq,
                        unsigned short* __restrict__ Wn_t, unsigned short* __restrict__ Wt_t) {
  int tx = threadIdx.x & 31, ty = threadIdx.x >> 5;
  int j = blockIdx.x * 32 + tx;               // NB index
  float inv = 1.0f / sqrtf(colsq[j]);
#pragma unroll
  for (int r = 0; r < 4; ++r) {
    int i = blockIdx.y * 32 + ty + r * 8;     // DB index
    unsigned short h = f2h(W[(size_t)i * NB + j] * inv);
    Wn_t[(((size_t)(i >> 4) * (NB / 16) + (j >> 4)) << 8) + (i & 15) * 16 + (j & 15)] = h;
    Wt_t[(((size_t)(j >> 4) * (DB / 16) + (i >> 4)) << 8) + (j & 15) * 16 + (i & 15)] = h;
  }
}

// Y (row-major fp32) -> Yh (tiled fp16) + ||Y||^2.
// Wave-per-row: fully coalesced 2KB reads; one atomic per block.
__global__ __launch_bounds__(256) void k_ynorm(const float* __restrict__ Y,
                                               unsigned short* __restrict__ Yh,
                                               float* __restrict__ slots) {
  __shared__ float part[4];
  int w = threadIdx.x >> 6, lane = threadIdx.x & 63;
  float s = 0.f;
#pragma unroll
  for (int rr = 0; rr < 4; ++rr) {
    int m = blockIdx.x * 16 + w * 4 + rr;     // 512 blocks x 16 rows
    const float* yrow = &Y[(size_t)m * DB + lane * 8];
    f4 v0 = *(const f4*)yrow;
    f4 v1 = *(const f4*)(yrow + 4);
    us8 h;
#pragma unroll
    for (int q = 0; q < 4; ++q) {
      h[q] = f2h(v0[q]);     s += v0[q] * v0[q];
      h[4 + q] = f2h(v1[q]); s += v1[q] * v1[q];
    }
    *(us8*)&Yh[(((size_t)(m >> 4) * 32 + (lane >> 1)) << 8) + (m & 15) * 16 + (lane & 1) * 8] = h;
  }
  for (int off = 32; off > 0; off >>= 1) s += __shfl_xor(s, off);
  if (lane == 0) part[w] = s;
  __syncthreads();
  if (threadIdx.x == 0) atomicAdd(&slots[SL_Y2], part[0] + part[1] + part[2] + part[3]);
}

// fp32 squaring: D = (S/tr)^2, accumulate trace(D)
__global__ __launch_bounds__(256) void k_sq(const float* __restrict__ S, float* __restrict__ D,
                                            const float* __restrict__ trIn, float* __restrict__ trOut) {
  __shared__ float tA[32][33], tB[32][33];
  int tx = threadIdx.x & 31, ty = threadIdx.x >> 5;
  int r0 = blockIdx.y * 32, c0 = blockIdx.x * 32;
  float inv = 1.0f / trIn[0];
  float acc[4] = {0.f, 0.f, 0.f, 0.f};
  for (int kt = 0; kt < 16; ++kt) {
    __syncthreads();
#pragma unroll
    for (int r = 0; r < 4; ++r) {
      tA[ty + r * 8][tx] = S[(size_t)(r0 + ty + r * 8) * DB + kt * 32 + tx];
      tB[ty + r * 8][tx] = S[(size_t)(kt * 32 + ty + r * 8) * DB + c0 + tx];
    }
    __syncthreads();
#pragma unroll
    for (int kk = 0; kk < 32; ++kk) {
      float b = tB[kk][tx];
#pragma unroll
      for (int r = 0; r < 4; ++r) acc[r] += tA[ty + r * 8][kk] * b;
    }
  }
  float inv2 = inv * inv;
#pragma unroll
  for (int r = 0; r < 4; ++r) {
    int row = r0 + ty + r * 8, col = c0 + tx;
    float v = acc[r] * inv2;
    D[(size_t)row * DB + col] = v;
    if (row == col) atomicAdd(trOut, v);
  }
}

__global__ void k_rayleigh(const float* __restrict__ Bm, const float* __restrict__ S,
                           float* __restrict__ slots) {
  int tid = blockIdx.x * 256 + threadIdx.x;
  float num = 0.f, den = 0.f;
  for (int i = tid; i < DB * DB; i += 256 * 256) {
    float s = S[i];
    num += Bm[i] * s;
    if ((i >> 9) == (i & 511)) den += s;
  }
  for (int off = 32; off > 0; off >>= 1) { num += __shfl_xor(num, off); den += __shfl_xor(den, off); }
  if ((threadIdx.x & 63) == 0) { atomicAdd(&slots[SL_NUM], num); atomicAdd(&slots[SL_DEN], den); }
}

__global__ void k_derive(float* slots, const float* __restrict__ Kp) {
  if (threadIdx.x == 0) {
    float cc = slots[SL_NUM] / slots[SL_DEN];
    slots[SL_C] = cc;
    float eta = 1.0f / cc;
    slots[SL_ETA] = eta;
    slots[SL_THR] = Kp[0] * eta;
  }
}

__global__ void k_norms(const float* __restrict__ slots, float* __restrict__ out) {
  int i = threadIdx.x;
  if (i < ITERS) out[i] = sqrtf(slots[SL_RES2 + i] / slots[SL_Y2]);
}

// ---------------- GEMM kernels ----------------
// B = Wn * Wn^T [512x512] row-major out, trace -> slots[SL_TR].
__global__ __launch_bounds__(256) void k_gemm_bbuild(const unsigned short* __restrict__ Wn_t,
                                                     float* __restrict__ Bm, float* __restrict__ slots) {
  accv_t acc[2][4];
  int w = threadIdx.x >> 6, lane = threadIdx.x & 63;
  int mt0 = blockIdx.y * 8 + w * 2, nt0 = blockIdx.x * 4;
  gemm_tt<2, 4, NB / 32>(Wn_t, NB / 16, Wn_t, NB / 16, mt0, nt0, acc);
  int l16 = lane & 15, quad = lane >> 4;
  float tr = 0.f;
#pragma unroll
  for (int mi = 0; mi < 2; ++mi)
#pragma unroll
    for (int ni = 0; ni < 4; ++ni) {
      int m = (mt0 + mi) * 16 + l16, nb = (nt0 + ni) * 16 + quad * 4;
      *(f4*)&Bm[(size_t)m * DB + nb] = acc[mi][ni];
#pragma unroll
      for (int r = 0; r < 4; ++r)
        if (m == nb + r) tr += acc[mi][ni][r];
    }
  if (tr != 0.f) atomicAdd(&slots[SL_TR], tr);
}

// Gamma0 = soft(eta*(Y@Wn), lam); Gh = Zh = Gamma0 (tiled).
// block 128x128, wave 64x64 (MI=4,NI=4), XCD-clustered grid 1024. (proven form)
__global__ __launch_bounds__(256) void k_gemm_init(const unsigned short* __restrict__ Yh,
                                                   const unsigned short* __restrict__ Wt_t,
                                                   const float* __restrict__ slots,
                                                   const float* __restrict__ Kp,
                                                   unsigned short* __restrict__ Gh,
                                                   unsigned short* __restrict__ Zh) {
  accv_t acc[4][4];
  int w = threadIdx.x >> 6;
  int h = blockIdx.x;
  int xcd = h & 7, slot = h >> 3;            // 128 slots per XCD
  int band = xcd * 8 + (slot >> 4);          // 64 bands of 128 rows
  int nt = slot & 15;                        // 16 n-groups of 128 cols
  int mt0 = band * 8 + (w >> 1) * 4, nt0 = nt * 8 + (w & 1) * 4;
  gemm_tt<4, 4, DB / 32>(Yh, DB / 16, Wt_t, DB / 16, mt0, nt0, acc);
  float eta = slots[SL_ETA], lam = Kp[0];
#pragma unroll
  for (int mi = 0; mi < 4; ++mi)
#pragma unroll
    for (int ni = 0; ni < 4; ++ni) {
      size_t tb = ctile_off(mt0 + mi, nt0 + ni, NB / 16);
      us4 gq;
#pragma unroll
      for (int r = 0; r < 4; ++r) gq[r] = f2h(softthr(acc[mi][ni][r] * eta, lam));
      *(us4*)&Gh[tb] = gq;
      *(us4*)&Zh[tb] = gq;
    }
}

// R = Z @ Wn^T - Y (tiled); ||R||^2.
// IN-BLOCK SPLIT-K: 512 threads = 8 waves = 2 khalf x 4 m-quarters.
// Each wave: MI=2,NI=4 over NKT=32 (half K). Upper khalf dumps acc to LDS
// (33-padded, conflict-free); lower adds + epilogue. Partials never leave
// the CU (r6's HBM round-trip eliminated). Grid 512 XCD-clustered ->
// 2 blocks/CU x 8 waves = 4 waves/SIMD (2x round-7) with half the K-chain.
__global__ __launch_bounds__(512) void k_gemm_res(const unsigned short* __restrict__ Zh,
                                                  const unsigned short* __restrict__ Wn_t,
                                                  const unsigned short* __restrict__ Yh,
                                                  unsigned short* __restrict__ Rh,
                                                  float* __restrict__ res2slot) {
  __shared__ float red[4][64][33];
  accv_t acc[2][4];
  int w = threadIdx.x >> 6, lane = threadIdx.x & 63;
  int wk = w >> 2, wm = w & 3;
  int h = blockIdx.x;
  int xcd = h & 7, slot = h >> 3;            // 64 slots per XCD
  int band = xcd * 8 + (slot >> 3);          // 64 bands of 128 rows
  int nt = slot & 7;                         // 8 n-groups of 64 cols
  int mt0 = band * 8 + wm * 2, nt0 = nt * 4;
  const size_t koff = (size_t)wk * 64 * 256;   // khalf: advance 64 k-tiles (r6-verified)
  gemm_tt<2, 4, NB / 64>(Zh + koff, NB / 16, Wn_t + koff, NB / 16, mt0, nt0, acc);
  if (wk == 1) {
#pragma unroll
    for (int mi = 0; mi < 2; ++mi)
#pragma unroll
      for (int ni = 0; ni < 4; ++ni)
#pragma unroll
        for (int r = 0; r < 4; ++r)
          red[wm][lane][mi * 16 + ni * 4 + r] = acc[mi][ni][r];
  }
  __syncthreads();
  if (wk == 0) {
    float s2 = 0.f;
#pragma unroll
    for (int mi = 0; mi < 2; ++mi)
#pragma unroll
      for (int ni = 0; ni < 4; ++ni) {
        size_t tb = ctile_off(mt0 + mi, nt0 + ni, DB / 16);
        us4 yq = *(const us4*)&Yh[tb];
        us4 rq;
#pragma unroll
        for (int r = 0; r < 4; ++r) {
          float rv = acc[mi][ni][r] + red[wm][lane][mi * 16 + ni * 4 + r] - h2f(yq[r]);
          rq[r] = f2h(rv);
          s2 += rv * rv;
        }
        *(us4*)&Rh[tb] = rq;
      }
    for (int off = 32; off > 0; off >>= 1) s2 += __shfl_xor(s2, off);
    if (lane == 0) atomicAdd(res2slot, s2);
  }
}

// G = R @ Wn ; gn = soft(Z - eta*G, lam/c); Z = gn + mom*(gn-Gamma_old); Gh = gn.
// block 128x128, wave 64x64 (MI=4,NI=4), XCD-clustered grid 1024. (proven form)
__global__ __launch_bounds__(256) void k_gemm_upd(const unsigned short* __restrict__ Rh,
                                                  const unsigned short* __restrict__ Wt_t,
                                                  const float* __restrict__ slots,
                                                  unsigned short* __restrict__ Gh,
                                                  unsigned short* __restrict__ Zh,
                                                  float* __restrict__ GammaOut,
                                                  float mom, int writeFinal) {
  accv_t acc[4][4];
  int w = threadIdx.x >> 6, lane = threadIdx.x & 63;
  int h = blockIdx.x;
  int xcd = h & 7, slot = h >> 3;            // 128 slots per XCD
  int band = xcd * 8 + (slot >> 4);          // 64 bands of 128 rows
  int nt = slot & 15;                        // 16 n-groups of 128 cols
  int mt0 = band * 8 + (w >> 1) * 4, nt0 = nt * 8 + (w & 1) * 4;
  gemm_tt<4, 4, DB / 32>(Rh, DB / 16, Wt_t, DB / 16, mt0, nt0, acc);
  int l16 = lane & 15, quad = lane >> 4;
  float eta = slots[SL_ETA], thr = slots[SL_THR];
#pragma unroll
  for (int mi = 0; mi < 4; ++mi)
#pragma unroll
    for (int ni = 0; ni < 4; ++ni) {
      size_t tb = ctile_off(mt0 + mi, nt0 + ni, NB / 16);
      us4 zq = *(const us4*)&Zh[tb];
      us4 gq = *(const us4*)&Gh[tb];
      us4 gho, zho;
      f4 gf;
#pragma unroll
      for (int r = 0; r < 4; ++r) {
        float z = h2f(zq[r]);
        float gold = h2f(gq[r]);
        float gn = softthr(z - eta * acc[mi][ni][r], thr);
        float zn = gn + mom * (gn - gold);
        gho[r] = f2h(gn);
        zho[r] = f2h(zn);
        gf[r] = gn;
      }
      *(us4*)&Gh[tb] = gho;
      *(us4*)&Zh[tb] = zho;
      if (writeFinal) {
        int m = (mt0 + mi) * 16 + l16, nb = (nt0 + ni) * 16 + quad * 4;
        *(f4*)&GammaOut[(size_t)m * NB + nb] = gf;
      }
    }
}

// X = Gamma @ Wn^T (row-major fp32 out). Same in-block split-K as res.
__global__ __launch_bounds__(512) void k_gemm_x(const unsigned short* __restrict__ Gh,
                                                const unsigned short* __restrict__ Wn_t,
                                                float* __restrict__ X) {
  __shared__ float red[4][64][33];
  accv_t acc[2][4];
  int w = threadIdx.x >> 6, lane = threadIdx.x & 63;
  int wk = w >> 2, wm = w & 3;
  int h = blockIdx.x;
  int xcd = h & 7, slot = h >> 3;
  int band = xcd * 8 + (slot >> 3);
  int nt = slot & 7;
  int mt0 = band * 8 + wm * 2, nt0 = nt * 4;
  const size_t koff = (size_t)wk * 64 * 256;
  gemm_tt<2, 4, NB / 64>(Gh + koff, NB / 16, Wn_t + koff, NB / 16, mt0, nt0, acc);
  if (wk == 1) {
#pragma unroll
    for (int mi = 0; mi < 2; ++mi)
#pragma unroll
      for (int ni = 0; ni < 4; ++ni)
#pragma unroll
        for (int r = 0; r < 4; ++r)
          red[wm][lane][mi * 16 + ni * 4 + r] = acc[mi][ni][r];
  }
  __syncthreads();
  if (wk == 0) {
    int l16 = lane & 15, quad = lane >> 4;
#pragma unroll
    for (int mi = 0; mi < 2; ++mi)
#pragma unroll
      for (int ni = 0; ni < 4; ++ni) {
        int m = (mt0 + mi) * 16 + l16, nb = (nt0 + ni) * 16 + quad * 4;
        f4 o;
#pragma unroll
        for (int r = 0; r < 4; ++r)
          o[r] = acc[mi][ni][r] + red[wm][lane][mi * 16 + ni * 4 + r];
        *(f4*)&X[(size_t)m * DB + nb] = o;
      }
  }
}

extern "C" void kernel_launch(void* const* d_in, const int* in_sizes, int n_in,
                              void* d_out, int out_size, void* d_ws, size_t ws_size,
                              hipStream_t stream) {
  const float* Y  = (const float*)d_in[0];
  const float* W  = (const float*)d_in[1];
  const float* Kp = (const float*)d_in[2];

  float* Xout     = (float*)d_out;
  float* GammaOut = Xout + (size_t)NR * DB;
  float* NormsOut = GammaOut + (size_t)NR * NB;

  char* p = (char*)d_ws;
  auto carve = [&](size_t bytes) -> void* {
    void* r = (void*)p; p += (bytes + 255) & ~(size_t)255; return r;
  };
  float* slots = (float*)carve(64 * 4);
  float* colsq = (float*)carve(NB * 4);
  float* Bmat  = (float*)carve((size_t)DB * DB * 4);
  float* S0    = (float*)carve((size_t)DB * DB * 4);
  float* S1    = (float*)carve((size_t)DB * DB * 4);
  unsigned short* Wn_t = (unsigned short*)carve((size_t)DB * NB * 2);
  unsigned short* Wt_t = (unsigned short*)carve((size_t)NB * DB * 2);
  unsigned short* Yh   = (unsigned short*)carve((size_t)NR * DB * 2);
  unsigned short* Rh   = (unsigned short*)carve((size_t)NR * DB * 2);
  unsigned short* Zh   = (unsigned short*)carve((size_t)NR * NB * 2);
  unsigned short* Gh   = (unsigned short*)carve((size_t)NR * NB * 2);

  k_zero<<<1, 256, 0, stream>>>(slots, colsq);
  k_colsq<<<dim3(NB / 256, DB / 64), 256, 0, stream>>>(W, colsq);
  k_wnorm<<<dim3(NB / 32, DB / 32), 256, 0, stream>>>(W, colsq, Wn_t, Wt_t);
  k_ynorm<<<512, 256, 0, stream>>>(Y, Yh, slots);

  // power method replacement: B = Wn Wn^T, then 9 trace-normalized squarings + Rayleigh
  k_gemm_bbuild<<<dim3(DB / 64, DB / 128), 256, 0, stream>>>(Wn_t, Bmat, slots);
  float* ss[2] = {S0, S1};
  for (int k = 0; k < NSQ; ++k) {
    const float* in = (k == 0) ? Bmat : ss[(k + 1) & 1];
    k_sq<<<dim3(16, 16), 256, 0, stream>>>(in, ss[k & 1], slots + SL_TR + k, slots + SL_TR + k + 1);
  }
  k_rayleigh<<<256, 256, 0, stream>>>(Bmat, ss[(NSQ + 1) & 1], slots);
  k_derive<<<1, 64, 0, stream>>>(slots, Kp);

  // FISTA
  k_gemm_init<<<1024, 256, 0, stream>>>(Yh, Wt_t, slots, Kp, Gh, Zh);
  double t = 1.0;
  for (int i = 0; i < ITERS; ++i) {
    k_gemm_res<<<512, 512, 0, stream>>>(Zh, Wn_t, Yh, Rh, slots + SL_RES2 + i);
    double tn = (1.0 + sqrt(1.0 + 4.0 * t * t)) / 2.0;
    float mom = (float)((t - 1.0) / tn);
    t = tn;
    k_gemm_upd<<<1024, 256, 0, stream>>>(Rh, Wt_t, slots, Gh, Zh, GammaOut,
                                         mom, (i == ITERS - 1) ? 1 : 0);
  }
  k_gemm_x<<<512, 512, 0, stream>>>(Gh, Wn_t, Xout);
  k_norms<<<1, 64, 0, stream>>>(slots, NormsOut);
}

// Round 9
// 2121.196 us; speedup vs baseline: 1.5627x; 1.1275x over previous
//
#include <hip/hip_runtime.h>
#include <cmath>

#define NR   8192   // rows of Y
#define DB   512    // signal dim n
#define NB   2048   // dictionary atoms m
#define ITERS 20
#define NSQ   9     // trace-normalized squarings of B

typedef _Float16 hfrag_t __attribute__((ext_vector_type(8)));  // 8 fp16 = 16B
typedef __attribute__((ext_vector_type(4))) float accv_t;      // 4 fp32
typedef unsigned short us4 __attribute__((ext_vector_type(4))); // 8B
typedef unsigned short us8 __attribute__((ext_vector_type(8))); // 16B
typedef float f4 __attribute__((ext_vector_type(4)));           // 16B

// scalar slots in ws
#define SL_Y2   0
#define SL_NUM  1
#define SL_DEN  2
#define SL_C    3
#define SL_ETA  4
#define SL_THR  5
#define SL_TR   6    // 6..15  traces
#define SL_RES2 16   // 16..35 per-iter ||R||^2

__device__ inline unsigned short f2h(float f) {
  _Float16 h = (_Float16)f;
  return __builtin_bit_cast(unsigned short, h);
}
__device__ inline float h2f(unsigned short u) {
  _Float16 h = __builtin_bit_cast(_Float16, u);
  return (float)h;
}
__device__ inline float softthr(float x, float t) {
  float a = fabsf(x) - t;
  return a > 0.f ? copysignf(a, x) : 0.f;
}

// ---- Fragment-native tiled layout ----
// 16x16 tile = 256 contiguous fp16, element (m,k) at m*16+k (row-major in tile).
// A-fragment for mfma_16x16x32 (operand-swapped): lane (l16,quad) needs
// A[m=l16][k=quad*8+j] j=0..7 -> tile kt*2+(quad>>1), bytes l16*32+(quad&1)*16:
// ONE 16B load per fragment; wave covers 512B contiguous. Same for B (n,k).
// C tile: lane owns (m=l16, n=quad*4+r) -> us4 at byte l16*32+quad*8.

// ---- barrier-free MFMA GEMM core: both operands tiled, no LDS ----
// EXACT round-0 proven text. Do NOT restructure (lambda/UNR/manual-PF all
// regressed in r1/r5/r6). Bound is L1 line throughput: (MI+NI) loads x 8
// cache-lines each per k-step; bigger MI/NI cuts TA cycles per MFMA.
template<int MI, int NI, int NKT>
__device__ inline void gemm_tt(const unsigned short* __restrict__ At, int NTka,
                               const unsigned short* __restrict__ Bt, int NTkb,
                               int mt0, int nt0, accv_t acc[MI][NI]) {
  const int lane = threadIdx.x & 63;
  const int l16 = lane & 15, quad = lane >> 4;
  const int off = l16 * 16 + (quad & 1) * 8;   // element offset within tile
  const int kh = quad >> 1;
#pragma unroll
  for (int mi = 0; mi < MI; ++mi)
#pragma unroll
    for (int ni = 0; ni < NI; ++ni) acc[mi][ni] = (accv_t){0.f, 0.f, 0.f, 0.f};

#pragma unroll 4
  for (int kt = 0; kt < NKT; ++kt) {
    const int ktile = (kt << 1) + kh;
    hfrag_t af[MI], bf[NI];
#pragma unroll
    for (int mi = 0; mi < MI; ++mi)
      af[mi] = *(const hfrag_t*)&At[(((size_t)(mt0 + mi) * NTka + ktile) << 8) + off];
#pragma unroll
    for (int ni = 0; ni < NI; ++ni)
      bf[ni] = *(const hfrag_t*)&Bt[(((size_t)(nt0 + ni) * NTkb + ktile) << 8) + off];
#pragma unroll
    for (int mi = 0; mi < MI; ++mi)
#pragma unroll
      for (int ni = 0; ni < NI; ++ni)
        acc[mi][ni] = __builtin_amdgcn_mfma_f32_16x16x32_f16(bf[ni], af[mi], acc[mi][ni], 0, 0, 0);
  }
}

// C-tile epilogue offset (element units) for tiled fp16 surfaces
__device__ inline size_t ctile_off(int mt, int nt, int NTn) {
  int lane = threadIdx.x & 63;
  return (((size_t)mt * NTn + nt) << 8) + (lane & 15) * 16 + (lane >> 4) * 4;
}

// ---------------- small kernels ----------------
__global__ void k_zero(float* slots, float* colsq) {
  if (threadIdx.x < 64) slots[threadIdx.x] = 0.f;
  for (int i = threadIdx.x; i < NB; i += 256) colsq[i] = 0.f;
}

// column sum-of-squares, row-split partials (grid (8 colgroups, 8 rowgroups))
__global__ void k_colsq(const float* __restrict__ W, float* __restrict__ colsq) {
  int j = blockIdx.x * 256 + threadIdx.x;     // column
  int r0 = blockIdx.y * 64;
  float s = 0.f;
  for (int i = 0; i < 64; ++i) { float v = W[(size_t)(r0 + i) * NB + j]; s += v * v; }
  atomicAdd(&colsq[j], s);
}

// normalize cols; emit tiled Wn_t [DB/16][NB/16] (elem (i,j)->i*16+j)
// and tiled Wt_t [NB/16][DB/16] (elem (j,i)->j*16+i)
__global__ void k_wnorm(const float* __restrict__ W, const float* __restrict__ colsq,
                        unsigned short* __restrict__ Wn_t, unsigned short* __restrict__ Wt_t) {
  int tx = threadIdx.x & 31, ty = threadIdx.x >> 5;
  int j = blockIdx.x * 32 + tx;               // NB index
  float inv = 1.0f / sqrtf(colsq[j]);
#pragma unroll
  for (int r = 0; r < 4; ++r) {
    int i = blockIdx.y * 32 + ty + r * 8;     // DB index
    unsigned short h = f2h(W[(size_t)i * NB + j] * inv);
    Wn_t[(((size_t)(i >> 4) * (NB / 16) + (j >> 4)) << 8) + (i & 15) * 16 + (j & 15)] = h;
    Wt_t[(((size_t)(j >> 4) * (DB / 16) + (i >> 4)) << 8) + (j & 15) * 16 + (i & 15)] = h;
  }
}

// Y (row-major fp32) -> Yh (tiled fp16) + ||Y||^2.
__global__ __launch_bounds__(256) void k_ynorm(const float* __restrict__ Y,
                                               unsigned short* __restrict__ Yh,
                                               float* __restrict__ slots) {
  __shared__ float part[4];
  int w = threadIdx.x >> 6, lane = threadIdx.x & 63;
  float s = 0.f;
#pragma unroll
  for (int rr = 0; rr < 4; ++rr) {
    int m = blockIdx.x * 16 + w * 4 + rr;     // 512 blocks x 16 rows
    const float* yrow = &Y[(size_t)m * DB + lane * 8];
    f4 v0 = *(const f4*)yrow;
    f4 v1 = *(const f4*)(yrow + 4);
    us8 h;
#pragma unroll
    for (int q = 0; q < 4; ++q) {
      h[q] = f2h(v0[q]);     s += v0[q] * v0[q];
      h[4 + q] = f2h(v1[q]); s += v1[q] * v1[q];
    }
    *(us8*)&Yh[(((size_t)(m >> 4) * 32 + (lane >> 1)) << 8) + (m & 15) * 16 + (lane & 1) * 8] = h;
  }
  for (int off = 32; off > 0; off >>= 1) s += __shfl_xor(s, off);
  if (lane == 0) part[w] = s;
  __syncthreads();
  if (threadIdx.x == 0) atomicAdd(&slots[SL_Y2], part[0] + part[1] + part[2] + part[3]);
}

// fp32 squaring: D = (S/tr)^2, accumulate trace(D)
__global__ __launch_bounds__(256) void k_sq(const float* __restrict__ S, float* __restrict__ D,
                                            const float* __restrict__ trIn, float* __restrict__ trOut) {
  __shared__ float tA[32][33], tB[32][33];
  int tx = threadIdx.x & 31, ty = threadIdx.x >> 5;
  int r0 = blockIdx.y * 32, c0 = blockIdx.x * 32;
  float inv = 1.0f / trIn[0];
  float acc[4] = {0.f, 0.f, 0.f, 0.f};
  for (int kt = 0; kt < 16; ++kt) {
    __syncthreads();
#pragma unroll
    for (int r = 0; r < 4; ++r) {
      tA[ty + r * 8][tx] = S[(size_t)(r0 + ty + r * 8) * DB + kt * 32 + tx];
      tB[ty + r * 8][tx] = S[(size_t)(kt * 32 + ty + r * 8) * DB + c0 + tx];
    }
    __syncthreads();
#pragma unroll
    for (int kk = 0; kk < 32; ++kk) {
      float b = tB[kk][tx];
#pragma unroll
      for (int r = 0; r < 4; ++r) acc[r] += tA[ty + r * 8][kk] * b;
    }
  }
  float inv2 = inv * inv;
#pragma unroll
  for (int r = 0; r < 4; ++r) {
    int row = r0 + ty + r * 8, col = c0 + tx;
    float v = acc[r] * inv2;
    D[(size_t)row * DB + col] = v;
    if (row == col) atomicAdd(trOut, v);
  }
}

__global__ void k_rayleigh(const float* __restrict__ Bm, const float* __restrict__ S,
                           float* __restrict__ slots) {
  int tid = blockIdx.x * 256 + threadIdx.x;
  float num = 0.f, den = 0.f;
  for (int i = tid; i < DB * DB; i += 256 * 256) {
    float s = S[i];
    num += Bm[i] * s;
    if ((i >> 9) == (i & 511)) den += s;
  }
  for (int off = 32; off > 0; off >>= 1) { num += __shfl_xor(num, off); den += __shfl_xor(den, off); }
  if ((threadIdx.x & 63) == 0) { atomicAdd(&slots[SL_NUM], num); atomicAdd(&slots[SL_DEN], den); }
}

__global__ void k_derive(float* slots, const float* __restrict__ Kp) {
  if (threadIdx.x == 0) {
    float cc = slots[SL_NUM] / slots[SL_DEN];
    slots[SL_C] = cc;
    float eta = 1.0f / cc;
    slots[SL_ETA] = eta;
    slots[SL_THR] = Kp[0] * eta;
  }
}

__global__ void k_norms(const float* __restrict__ slots, float* __restrict__ out) {
  int i = threadIdx.x;
  if (i < ITERS) out[i] = sqrtf(slots[SL_RES2 + i] / slots[SL_Y2]);
}

// ---------------- GEMM kernels ----------------
// B = Wn * Wn^T [512x512] row-major out, trace -> slots[SL_TR]. (runs once)
__global__ __launch_bounds__(256) void k_gemm_bbuild(const unsigned short* __restrict__ Wn_t,
                                                     float* __restrict__ Bm, float* __restrict__ slots) {
  accv_t acc[2][4];
  int w = threadIdx.x >> 6, lane = threadIdx.x & 63;
  int mt0 = blockIdx.y * 8 + w * 2, nt0 = blockIdx.x * 4;
  gemm_tt<2, 4, NB / 32>(Wn_t, NB / 16, Wn_t, NB / 16, mt0, nt0, acc);
  int l16 = lane & 15, quad = lane >> 4;
  float tr = 0.f;
#pragma unroll
  for (int mi = 0; mi < 2; ++mi)
#pragma unroll
    for (int ni = 0; ni < 4; ++ni) {
      int m = (mt0 + mi) * 16 + l16, nb = (nt0 + ni) * 16 + quad * 4;
      *(f4*)&Bm[(size_t)m * DB + nb] = acc[mi][ni];
#pragma unroll
      for (int r = 0; r < 4; ++r)
        if (m == nb + r) tr += acc[mi][ni][r];
    }
  if (tr != 0.f) atomicAdd(&slots[SL_TR], tr);
}

// Gamma0 = soft(eta*(Y@Wn), lam); Gh = Zh = Gamma0 (tiled). (runs once, proven)
__global__ __launch_bounds__(256) void k_gemm_init(const unsigned short* __restrict__ Yh,
                                                   const unsigned short* __restrict__ Wt_t,
                                                   const float* __restrict__ slots,
                                                   const float* __restrict__ Kp,
                                                   unsigned short* __restrict__ Gh,
                                                   unsigned short* __restrict__ Zh) {
  accv_t acc[4][4];
  int w = threadIdx.x >> 6;
  int h = blockIdx.x;
  int xcd = h & 7, slot = h >> 3;            // 128 slots per XCD
  int band = xcd * 8 + (slot >> 4);          // 64 bands of 128 rows
  int nt = slot & 15;                        // 16 n-groups of 128 cols
  int mt0 = band * 8 + (w >> 1) * 4, nt0 = nt * 8 + (w & 1) * 4;
  gemm_tt<4, 4, DB / 32>(Yh, DB / 16, Wt_t, DB / 16, mt0, nt0, acc);
  float eta = slots[SL_ETA], lam = Kp[0];
#pragma unroll
  for (int mi = 0; mi < 4; ++mi)
#pragma unroll
    for (int ni = 0; ni < 4; ++ni) {
      size_t tb = ctile_off(mt0 + mi, nt0 + ni, NB / 16);
      us4 gq;
#pragma unroll
      for (int r = 0; r < 4; ++r) gq[r] = f2h(softthr(acc[mi][ni][r] * eta, lam));
      *(us4*)&Gh[tb] = gq;
      *(us4*)&Zh[tb] = gq;
    }
}

// R = Z @ Wn^T - Y (tiled); ||R||^2.
// In-block split-K2 with MI=4,NI=4: 8 waves = 2 khalf x 4 m-waves, each wave
// 64m x 64n over half-K (0.5 loads/MFMA, was 0.75). Block 256m x 64n, grid 256
// XCD-clustered (1 block/CU, 2 waves/SIMD). Partials reduced in padded LDS.
__global__ __launch_bounds__(512) void k_gemm_res(const unsigned short* __restrict__ Zh,
                                                  const unsigned short* __restrict__ Wn_t,
                                                  const unsigned short* __restrict__ Yh,
                                                  unsigned short* __restrict__ Rh,
                                                  float* __restrict__ res2slot) {
  __shared__ float red[4][64][65];
  accv_t acc[4][4];
  int w = threadIdx.x >> 6, lane = threadIdx.x & 63;
  int wk = w >> 2, wm = w & 3;
  int h = blockIdx.x;
  int xcd = h & 7, slot = h >> 3;            // 32 slots per XCD
  int band = xcd * 4 + (slot >> 3);          // 32 bands of 256 rows
  int nt = slot & 7;                         // 8 n-groups of 64 cols
  int mt0 = band * 16 + wm * 4, nt0 = nt * 4;
  const size_t koff = (size_t)wk * 64 * 256;   // khalf: advance 64 k-tiles (r8-verified)
  gemm_tt<4, 4, NB / 64>(Zh + koff, NB / 16, Wn_t + koff, NB / 16, mt0, nt0, acc);
  if (wk == 1) {
#pragma unroll
    for (int mi = 0; mi < 4; ++mi)
#pragma unroll
      for (int ni = 0; ni < 4; ++ni)
#pragma unroll
        for (int r = 0; r < 4; ++r)
          red[wm][lane][mi * 16 + ni * 4 + r] = acc[mi][ni][r];
  }
  __syncthreads();
  if (wk == 0) {
    float s2 = 0.f;
#pragma unroll
    for (int mi = 0; mi < 4; ++mi)
#pragma unroll
      for (int ni = 0; ni < 4; ++ni) {
        size_t tb = ctile_off(mt0 + mi, nt0 + ni, DB / 16);
        us4 yq = *(const us4*)&Yh[tb];
        us4 rq;
#pragma unroll
        for (int r = 0; r < 4; ++r) {
          float rv = acc[mi][ni][r] + red[wm][lane][mi * 16 + ni * 4 + r] - h2f(yq[r]);
          rq[r] = f2h(rv);
          s2 += rv * rv;
        }
        *(us4*)&Rh[tb] = rq;
      }
    for (int off = 32; off > 0; off >>= 1) s2 += __shfl_xor(s2, off);
    if (lane == 0) atomicAdd(res2slot, s2);
  }
}

// G = R @ Wn ; gn = soft(Z - eta*G, lam/c); Z = gn + mom*(gn-Gamma_old); Gh = gn.
// MI=8,NI=4 (wave 128m x 64n): 12 loads / 32 MFMA = 0.375 loads/MFMA.
// Block 128m x 256n (4 n-waves share A lines in L1), grid 512 XCD-clustered
// (2 blocks/CU = 2 waves/SIMD). launch_bounds(256,2) caps VGPR at 256 so the
// allocator cannot spill chasing occupancy the grid can't deliver.
__global__ __launch_bounds__(256, 2) void k_gemm_upd(const unsigned short* __restrict__ Rh,
                                                     const unsigned short* __restrict__ Wt_t,
                                                     const float* __restrict__ slots,
                                                     unsigned short* __restrict__ Gh,
                                                     unsigned short* __restrict__ Zh,
                                                     float* __restrict__ GammaOut,
                                                     float mom, int writeFinal) {
  accv_t acc[8][4];
  int w = threadIdx.x >> 6, lane = threadIdx.x & 63;
  int h = blockIdx.x;
  int xcd = h & 7, slot = h >> 3;            // 64 slots per XCD
  int band = xcd * 8 + (slot >> 3);          // 64 m-bands of 128 rows
  int ng = slot & 7;                         // 8 n-groups of 256 cols
  int mt0 = band * 8, nt0 = ng * 16 + w * 4;
  gemm_tt<8, 4, DB / 32>(Rh, DB / 16, Wt_t, DB / 16, mt0, nt0, acc);
  int l16 = lane & 15, quad = lane >> 4;
  float eta = slots[SL_ETA], thr = slots[SL_THR];
#pragma unroll
  for (int mi = 0; mi < 8; ++mi)
#pragma unroll
    for (int ni = 0; ni < 4; ++ni) {
      size_t tb = ctile_off(mt0 + mi, nt0 + ni, NB / 16);
      us4 zq = *(const us4*)&Zh[tb];
      us4 gq = *(const us4*)&Gh[tb];
      us4 gho, zho;
      f4 gf;
#pragma unroll
      for (int r = 0; r < 4; ++r) {
        float z = h2f(zq[r]);
        float gold = h2f(gq[r]);
        float gn = softthr(z - eta * acc[mi][ni][r], thr);
        float zn = gn + mom * (gn - gold);
        gho[r] = f2h(gn);
        zho[r] = f2h(zn);
        gf[r] = gn;
      }
      *(us4*)&Gh[tb] = gho;
      *(us4*)&Zh[tb] = zho;
      if (writeFinal) {
        int m = (mt0 + mi) * 16 + l16, nb = (nt0 + ni) * 16 + quad * 4;
        *(f4*)&GammaOut[(size_t)m * NB + nb] = gf;
      }
    }
}

// X = Gamma @ Wn^T (row-major fp32 out). Same split-K2 MI=4 structure as res.
__global__ __launch_bounds__(512) void k_gemm_x(const unsigned short* __restrict__ Gh,
                                                const unsigned short* __restrict__ Wn_t,
                                                float* __restrict__ X) {
  __shared__ float red[4][64][65];
  accv_t acc[4][4];
  int w = threadIdx.x >> 6, lane = threadIdx.x & 63;
  int wk = w >> 2, wm = w & 3;
  int h = blockIdx.x;
  int xcd = h & 7, slot = h >> 3;
  int band = xcd * 4 + (slot >> 3);
  int nt = slot & 7;
  int mt0 = band * 16 + wm * 4, nt0 = nt * 4;
  const size_t koff = (size_t)wk * 64 * 256;
  gemm_tt<4, 4, NB / 64>(Gh + koff, NB / 16, Wn_t + koff, NB / 16, mt0, nt0, acc);
  if (wk == 1) {
#pragma unroll
    for (int mi = 0; mi < 4; ++mi)
#pragma unroll
      for (int ni = 0; ni < 4; ++ni)
#pragma unroll
        for (int r = 0; r < 4; ++r)
          red[wm][lane][mi * 16 + ni * 4 + r] = acc[mi][ni][r];
  }
  __syncthreads();
  if (wk == 0) {
    int l16 = lane & 15, quad = lane >> 4;
#pragma unroll
    for (int mi = 0; mi < 4; ++mi)
#pragma unroll
      for (int ni = 0; ni < 4; ++ni) {
        int m = (mt0 + mi) * 16 + l16, nb = (nt0 + ni) * 16 + quad * 4;
        f4 o;
#pragma unroll
        for (int r = 0; r < 4; ++r)
          o[r] = acc[mi][ni][r] + red[wm][lane][mi * 16 + ni * 4 + r];
        *(f4*)&X[(size_t)m * DB + nb] = o;
      }
  }
}

extern "C" void kernel_launch(void* const* d_in, const int* in_sizes, int n_in,
                              void* d_out, int out_size, void* d_ws, size_t ws_size,
                              hipStream_t stream) {
  const float* Y  = (const float*)d_in[0];
  const float* W  = (const float*)d_in[1];
  const float* Kp = (const float*)d_in[2];

  float* Xout     = (float*)d_out;
  float* GammaOut = Xout + (size_t)NR * DB;
  float* NormsOut = GammaOut + (size_t)NR * NB;

  char* p = (char*)d_ws;
  auto carve = [&](size_t bytes) -> void* {
    void* r = (void*)p; p += (bytes + 255) & ~(size_t)255; return r;
  };
  float* slots = (float*)carve(64 * 4);
  float* colsq = (float*)carve(NB * 4);
  float* Bmat  = (float*)carve((size_t)DB * DB * 4);
  float* S0    = (float*)carve((size_t)DB * DB * 4);
  float* S1    = (float*)carve((size_t)DB * DB * 4);
  unsigned short* Wn_t = (unsigned short*)carve((size_t)DB * NB * 2);
  unsigned short* Wt_t = (unsigned short*)carve((size_t)NB * DB * 2);
  unsigned short* Yh   = (unsigned short*)carve((size_t)NR * DB * 2);
  unsigned short* Rh   = (unsigned short*)carve((size_t)NR * DB * 2);
  unsigned short* Zh   = (unsigned short*)carve((size_t)NR * NB * 2);
  unsigned short* Gh   = (unsigned short*)carve((size_t)NR * NB * 2);

  k_zero<<<1, 256, 0, stream>>>(slots, colsq);
  k_colsq<<<dim3(NB / 256, DB / 64), 256, 0, stream>>>(W, colsq);
  k_wnorm<<<dim3(NB / 32, DB / 32), 256, 0, stream>>>(W, colsq, Wn_t, Wt_t);
  k_ynorm<<<512, 256, 0, stream>>>(Y, Yh, slots);

  // power method replacement: B = Wn Wn^T, then 9 trace-normalized squarings + Rayleigh
  k_gemm_bbuild<<<dim3(DB / 64, DB / 128), 256, 0, stream>>>(Wn_t, Bmat, slots);
  float* ss[2] = {S0, S1};
  for (int k = 0; k < NSQ; ++k) {
    const float* in = (k == 0) ? Bmat : ss[(k + 1) & 1];
    k_sq<<<dim3(16, 16), 256, 0, stream>>>(in, ss[k & 1], slots + SL_TR + k, slots + SL_TR + k + 1);
  }
  k_rayleigh<<<256, 256, 0, stream>>>(Bmat, ss[(NSQ + 1) & 1], slots);
  k_derive<<<1, 64, 0, stream>>>(slots, Kp);

  // FISTA
  k_gemm_init<<<1024, 256, 0, stream>>>(Yh, Wt_t, slots, Kp, Gh, Zh);
  double t = 1.0;
  for (int i = 0; i < ITERS; ++i) {
    k_gemm_res<<<256, 512, 0, stream>>>(Zh, Wn_t, Yh, Rh, slots + SL_RES2 + i);
    double tn = (1.0 + sqrt(1.0 + 4.0 * t * t)) / 2.0;
    float mom = (float)((t - 1.0) / tn);
    t = tn;
    k_gemm_upd<<<512, 256, 0, stream>>>(Rh, Wt_t, slots, Gh, Zh, GammaOut,
                                        mom, (i == ITERS - 1) ? 1 : 0);
  }
  k_gemm_x<<<256, 512, 0, stream>>>(Gh, Wn_t, Xout);
  k_norms<<<1, 64, 0, stream>>>(slots, NormsOut);
}